// Round 9
// baseline (1118.171 us; speedup 1.0000x reference)
//
#include <hip/hip_runtime.h>

// GeneratorDecoder: 128-step LSTM (H=32) + gumbel-argmax head (P=7), B=32768.
// Round 9: FOUR batches per wave at the SAME 64-VGPR weight footprint as
// round 8. Lane l owns gate rows l (i|f) and l+64 (g|o) packed f32x2; the
// weight set is reused by 4 independent gate chains (batches b0..b0+3).
// After one xor-32 exchange per batch, each lane runs TWO independent cells
// (lanes<32 -> batches 0,2; lanes>=32 -> 1,3). Argmax butterfly covers all
// 4 batches in one pass (16-lane groups). All per-batch FP chains verbatim
// round 8 (bit-identical trajectory). Gumbel noise precomputed into d_ws.

#define Hh 32
#define Pp 7
#define NDd 8

typedef float f32x2 __attribute__((ext_vector_type(2)));

static __device__ __forceinline__ f32x2 fma2(f32x2 w, float h, f32x2 a) {
  return __builtin_elementwise_fma(w, (f32x2){h, h}, a);
}

__global__ void gumbel_noise_kernel(const float4* __restrict__ u,
                                    float4* __restrict__ o, int n4) {
  int i = blockIdx.x * blockDim.x + threadIdx.x;
  int stride = gridDim.x * blockDim.x;
  for (; i < n4; i += stride) {
    float4 v = u[i];
    float4 r;
    r.x = -logf(-logf(v.x + 1e-20f) + 1e-20f);
    r.y = -logf(-logf(v.y + 1e-20f) + 1e-20f);
    r.z = -logf(-logf(v.z + 1e-20f) + 1e-20f);
    r.w = -logf(-logf(v.w + 1e-20f) + 1e-20f);
    o[i] = r;
  }
}

template <int PRE>
__global__ __launch_bounds__(64, 4) void gen_decoder_kernel(
    const float* __restrict__ h_n, const float* __restrict__ c_n,
    const float* __restrict__ noise, const float* __restrict__ gsrc,
    const float* __restrict__ W_init, const float* __restrict__ b_init,
    const float* __restrict__ W_ih, const float* __restrict__ W_hh,
    const float* __restrict__ b_ih, const float* __restrict__ b_hh,
    const float* __restrict__ W_head, const float* __restrict__ b_head,
    float* __restrict__ out, int B, int T)
{
  __shared__ f32x2 sTIG[8 * 32];   // [k][j] = {v(j,k),    v(64+j,k)}  (i,g rows)
  __shared__ f32x2 sTFO[8 * 32];   // [k][j] = {v(32+j,k), v(96+j,k)}  (f,o rows)
  __shared__ __align__(16) float sm_h[4 * 36];   // per-batch h, stride 36
  __shared__ __align__(16) float smL[4][56];     // 8 steps x 7 logits
  __shared__ __align__(16) float smS[4][56];     // 8 steps x 7 samples

  const int l    = threadIdx.x;     // one wave per block
  const int half = l >> 5;
  const int j    = l & 31;          // state slot
  const int b0   = blockIdx.x * 4;
  const int bF   = b0 + half;       // cell-pass-1 batch for this lane
  const int bS   = b0 + 2 + half;   // cell-pass-2 batch for this lane

  // fused W_ih/bias tables (wave-local, in-order: no barrier needed)
  for (int i = l; i < 8 * 32; i += 64) {
    int k = i >> 5, jj = i & 31;
    float vi = b_ih[jj]      + b_hh[jj]      + ((k < 7) ? W_ih[jj * 7 + k]        : 0.f);
    float vf = b_ih[32 + jj] + b_hh[32 + jj] + ((k < 7) ? W_ih[(32 + jj) * 7 + k] : 0.f);
    float vg = b_ih[64 + jj] + b_hh[64 + jj] + ((k < 7) ? W_ih[(64 + jj) * 7 + k] : 0.f);
    float vo = b_ih[96 + jj] + b_hh[96 + jj] + ((k < 7) ? W_ih[(96 + jj) * 7 + k] : 0.f);
    sTIG[i] = (f32x2){vi, vg};
    sTFO[i] = (f32x2){vf, vo};
  }

  // ---- h0 init for both owned batches (x dies before weight regs live) ----
  {
    float x[Hh + NDd];
#pragma unroll
    for (int i = 0; i < 8; i++)
      ((float4*)x)[i] = *(const float4*)&h_n[(size_t)bF * Hh + 4 * i];
    ((float4*)x)[8] = *(const float4*)&noise[(size_t)bF * NDd];
    ((float4*)x)[9] = *(const float4*)&noise[(size_t)bF * NDd + 4];
    float a = b_init[j];
    const float* wr = &W_init[j * (Hh + NDd)];
#pragma unroll
    for (int k = 0; k < Hh + NDd; k++) a = fmaf(wr[k], x[k], a);
    sm_h[half * 36 + j] = a;
  }
  {
    float x[Hh + NDd];
#pragma unroll
    for (int i = 0; i < 8; i++)
      ((float4*)x)[i] = *(const float4*)&h_n[(size_t)bS * Hh + 4 * i];
    ((float4*)x)[8] = *(const float4*)&noise[(size_t)bS * NDd];
    ((float4*)x)[9] = *(const float4*)&noise[(size_t)bS * NDd + 4];
    float a = b_init[j];
    const float* wr = &W_init[j * (Hh + NDd)];
#pragma unroll
    for (int k = 0; k < Hh + NDd; k++) a = fmaf(wr[k], x[k], a);
    sm_h[(2 + half) * 36 + j] = a;
  }
  float cF = c_n[(size_t)bF * Hh + j];
  float cS = c_n[(size_t)bS * Hh + j];

  // ---- recurrent weights: rows rA = l (i|f row j), rB = l+64 (g|o row j),
  //      packed {rA, rB} -> 64 VGPRs/lane, shared by all four batches ----
  f32x2 wPK[32];
  {
    const float* WA = W_hh + (size_t)l * Hh;
    const float* WB = W_hh + (size_t)(l + 64) * Hh;
#pragma unroll
    for (int kc = 0; kc < 8; kc++) {
      float4 wa = *(const float4*)&WA[4 * kc];
      float4 wb = *(const float4*)&WB[4 * kc];
      wPK[4 * kc + 0] = (f32x2){wa.x, wb.x};
      wPK[4 * kc + 1] = (f32x2){wa.y, wb.y};
      wPK[4 * kc + 2] = (f32x2){wa.z, wb.z};
      wPK[4 * kc + 3] = (f32x2){wa.w, wb.w};
    }
  }
  const f32x2* tbl = half ? sTFO : sTIG;   // own rows' init table

  // head weights: within each half, lane 4p+q (p<7) holds W_head[p][q+4m]
  const int hp = (l & 31) >> 2;
  const int hq = l & 3;
  float whead[8];
  float bh = 0.f;
  if (hp < 7) {
#pragma unroll
    for (int m = 0; m < 8; m++) whead[m] = W_head[hp * Hh + hq + 4 * m];
    bh = b_head[hp];
  } else {
#pragma unroll
    for (int m = 0; m < 8; m++) whead[m] = 0.f;
  }

  // candidate role: group g16 = l>>4 owns batch b0+g16; cp = l&15 (cand <7)
  const int g16 = l >> 4;
  const int cp  = l & 15;
  const int cpc = (cp < 7) ? cp : 6;
  const float* gL = gsrc + (size_t)(b0 + g16) * Pp + cpc;
  const size_t strideT = (size_t)B * Pp;
  const size_t SOFF = (size_t)B * T * Pp;   // samples block offset (floats)

  int k0 = 7, k1 = 7, k2 = 7, k3 = 7;   // y0 = 0 -> bias-only column
  float* outF = out + (size_t)bF * T * Pp;
  float* outS_ = out + (size_t)bS * T * Pp;

  for (int t = 0; t < T; ++t) {
    // gumbel noise for this step (independent of recurrence -> issue early)
    float nv;
    if constexpr (PRE) {
      nv = gL[(size_t)t * strideT];
    } else {
      float uv = gL[(size_t)t * strideT];
      nv = -logf(-logf(uv + 1e-20f) + 1e-20f);   // exact same text
    }

    // four packed gate chains (k-ascending, bit-identical per row)
    f32x2 a0 = tbl[(k0 << 5) + j];
    f32x2 a1 = tbl[(k1 << 5) + j];
    f32x2 a2 = tbl[(k2 << 5) + j];
    f32x2 a3 = tbl[(k3 << 5) + j];
#pragma unroll
    for (int kc = 0; kc < 8; kc++) {
      float4 h0v = *(const float4*)&sm_h[0 * 36 + 4 * kc];   // uniform reads
      float4 h1v = *(const float4*)&sm_h[1 * 36 + 4 * kc];
      float4 h2v = *(const float4*)&sm_h[2 * 36 + 4 * kc];
      float4 h3v = *(const float4*)&sm_h[3 * 36 + 4 * kc];
      a0 = fma2(wPK[4 * kc + 0], h0v.x, a0);
      a1 = fma2(wPK[4 * kc + 0], h1v.x, a1);
      a2 = fma2(wPK[4 * kc + 0], h2v.x, a2);
      a3 = fma2(wPK[4 * kc + 0], h3v.x, a3);
      a0 = fma2(wPK[4 * kc + 1], h0v.y, a0);
      a1 = fma2(wPK[4 * kc + 1], h1v.y, a1);
      a2 = fma2(wPK[4 * kc + 1], h2v.y, a2);
      a3 = fma2(wPK[4 * kc + 1], h3v.y, a3);
      a0 = fma2(wPK[4 * kc + 2], h0v.z, a0);
      a1 = fma2(wPK[4 * kc + 2], h1v.z, a1);
      a2 = fma2(wPK[4 * kc + 2], h2v.z, a2);
      a3 = fma2(wPK[4 * kc + 2], h3v.z, a3);
      a0 = fma2(wPK[4 * kc + 3], h0v.w, a0);
      a1 = fma2(wPK[4 * kc + 3], h1v.w, a1);
      a2 = fma2(wPK[4 * kc + 3], h2v.w, a2);
      a3 = fma2(wPK[4 * kc + 3], h3v.w, a3);
    }

    // exchange: assemble (i,f,g,o) per batch across the lane pair
    float x0x = __shfl_xor(a0.x, 32), x0y = __shfl_xor(a0.y, 32);
    float x1x = __shfl_xor(a1.x, 32), x1y = __shfl_xor(a1.y, 32);
    float x2x = __shfl_xor(a2.x, 32), x2y = __shfl_xor(a2.y, 32);
    float x3x = __shfl_xor(a3.x, 32), x3y = __shfl_xor(a3.y, 32);
    const bool lo = (l < 32);
    float iF = lo ? a0.x : x1x;   // cell pass 1: lanes<32 batch 0, lanes>=32 batch 1
    float gF = lo ? a0.y : x1y;
    float fF = lo ? x0x : a1.x;
    float oF = lo ? x0y : a1.y;
    float iS = lo ? a2.x : x3x;   // cell pass 2: batches 2 / 3
    float gS = lo ? a2.y : x3y;
    float fS = lo ? x2x : a3.x;
    float oS = lo ? x2y : a3.y;

    // two independent cells (exact expression text of rounds 1-8)
    float igF = 1.f / (1.f + expf(-iF));
    float fgF = 1.f / (1.f + expf(-fF));
    float ggF = tanhf(gF);
    float ogF = 1.f / (1.f + expf(-oF));
    float igS = 1.f / (1.f + expf(-iS));
    float fgS = 1.f / (1.f + expf(-fS));
    float ggS = tanhf(gS);
    float ogS = 1.f / (1.f + expf(-oS));
    float ccF = fgF * cF + igF * ggF;
    float ccS = fgS * cS + igS * ggS;
    cF = ccF;
    cS = ccS;
    float hjF = ogF * tanhf(ccF);
    float hjS = ogS * tanhf(ccS);
    sm_h[half * 36 + j] = hjF;
    sm_h[(2 + half) * 36 + j] = hjS;

    // head: two passes per lane (own half's two batches), same reduce shape
    float lgF = 0.f, lgS = 0.f;
    if (hp < 7) {
#pragma unroll
      for (int m = 0; m < 8; m++)
        lgF = fmaf(whead[m], sm_h[half * 36 + hq + 4 * m], lgF);
      lgF += __shfl_xor(lgF, 1);
      lgF += __shfl_xor(lgF, 2);
      lgF += bh;
#pragma unroll
      for (int m = 0; m < 8; m++)
        lgS = fmaf(whead[m], sm_h[(2 + half) * 36 + hq + 4 * m], lgS);
      lgS += __shfl_xor(lgS, 1);
      lgS += __shfl_xor(lgS, 2);
      lgS += bh;
    }

    // fan logit (batch g16, product cpc) to candidate lane
    int srcq = ((g16 & 1) << 5) + 4 * cpc;
    float LrF = __shfl(lgF, srcq);
    float LrS = __shfl(lgS, srcq);
    float Lr = (g16 < 2) ? LrF : LrS;

    // 8-candidate lowest-index argmax butterfly; 4 batches in one pass
    float bestv = (cp < 7) ? (Lr + nv) : -__builtin_inff();
    int besti = cp;
#pragma unroll
    for (int mask = 1; mask <= 4; mask <<= 1) {
      float ov = __shfl_xor(bestv, mask);
      int   oi = __shfl_xor(besti, mask);
      if (ov > bestv || (ov == bestv && oi < besti)) { bestv = ov; besti = oi; }
    }
    k0 = __shfl(besti, 0);
    k1 = __shfl(besti, 16);
    k2 = __shfl(besti, 32);
    k3 = __shfl(besti, 48);

    // stage outputs (quad leaders p<7 of each half, both owned batches)
    if (hp < 7 && hq == 0) {
      int t8 = (t & 7) * Pp + hp;
      int kF = half ? k1 : k0;
      int kS2 = half ? k3 : k2;
      smL[half][t8] = lgF;
      smS[half][t8] = (kF == hp) ? 1.f : 0.f;
      smL[2 + half][t8] = lgS;
      smS[2 + half][t8] = (kS2 == hp) ? 1.f : 0.f;
    }

    // flush every 8 steps: 14 float4 per batch, 4 batches per wave
    if ((t & 7) == 7) {
      int r = l & 31;
      if (r < 14) {
        size_t o = (size_t)(t - 7) * Pp + 4 * r;
        *(float4*)&outF[o]         = *(const float4*)&smL[half][4 * r];
        *(float4*)&outF[o + SOFF]  = *(const float4*)&smS[half][4 * r];
        *(float4*)&outS_[o]        = *(const float4*)&smL[2 + half][4 * r];
        *(float4*)&outS_[o + SOFF] = *(const float4*)&smS[2 + half][4 * r];
      }
    } else if (t == T - 1) {
      int t0 = t & ~7;
      int cnt = (t - t0 + 1) * Pp;
      for (int i = l & 31; i < cnt; i += 32) {
        size_t o = (size_t)t0 * Pp + i;
        outF[o]         = smL[half][i];
        outF[o + SOFF]  = smS[half][i];
        outS_[o]        = smL[2 + half][i];
        outS_[o + SOFF] = smS[2 + half][i];
      }
    }
  }
}

extern "C" void kernel_launch(void* const* d_in, const int* in_sizes, int n_in,
                              void* d_out, int out_size, void* d_ws, size_t ws_size,
                              hipStream_t stream) {
  const float* h_n     = (const float*)d_in[0];
  const float* c_n     = (const float*)d_in[1];
  const float* noise   = (const float*)d_in[2];
  const float* gumbel  = (const float*)d_in[3];
  const float* W_init  = (const float*)d_in[4];
  const float* b_init  = (const float*)d_in[5];
  const float* W_ih    = (const float*)d_in[6];
  const float* W_hh    = (const float*)d_in[7];
  const float* b_ih    = (const float*)d_in[8];
  const float* b_hh    = (const float*)d_in[9];
  const float* W_head  = (const float*)d_in[10];
  const float* b_head  = (const float*)d_in[11];

  int B = in_sizes[0] / Hh;                 // 32768
  int n = in_sizes[3];                      // T*B*P
  int T = n / (B * Pp);                     // 128
  size_t nbytes = (size_t)n * sizeof(float);
  bool pre = (ws_size >= nbytes) && (n % 4 == 0);

  if (pre) {
    gumbel_noise_kernel<<<2048, 256, 0, stream>>>(
        (const float4*)gumbel, (float4*)d_ws, n / 4);
    gen_decoder_kernel<1><<<dim3(B / 4), dim3(64), 0, stream>>>(
        h_n, c_n, noise, (const float*)d_ws, W_init, b_init, W_ih, W_hh,
        b_ih, b_hh, W_head, b_head, (float*)d_out, B, T);
  } else {
    gen_decoder_kernel<0><<<dim3(B / 4), dim3(64), 0, stream>>>(
        h_n, c_n, noise, gumbel, W_init, b_init, W_ih, W_hh,
        b_ih, b_hh, W_head, b_head, (float*)d_out, B, T);
  }
}

// Round 10
// 971.692 us; speedup vs baseline: 1.1507x; 1.1507x over previous
//
#include <hip/hip_runtime.h>

// GeneratorDecoder: 128-step LSTM (H=32) + gumbel-argmax head (P=7), B=32768.
// Round 10 = round 8 (986us, validated optimum: 2 batches/wave, lane l owns
// gate rows l (i|f) and l+64 (g|o) packed f32x2 = 64 weight VGPRs, one cell
// per lane after one xor-32 exchange, 4 waves/SIMD at the 128-reg knife edge)
// plus zero-risk trims:
//  1) gumbel prekernel removed; u_{t+1} loaded at top of step t and noise
//     computed in-kernel with the EXACT same expression text (independent of
//     the recurrence -> fills the latency bubble, saves ~47us prekernel wall
//     + 234MB HBM round-trip).
//  2) head block unguarded (lanes 28-31 compute zeros via zeroed whead/bh);
//     staging writes remain guarded. Removes exec-mask juggling per step.
// All FP chains / reduce trees / tie-breaks verbatim -> bit-identical.

#define Hh 32
#define Pp 7
#define NDd 8

typedef float f32x2 __attribute__((ext_vector_type(2)));

static __device__ __forceinline__ f32x2 fma2(f32x2 w, float h, f32x2 a) {
  return __builtin_elementwise_fma(w, (f32x2){h, h}, a);
}

__global__ __launch_bounds__(64, 4) void gen_decoder_kernel(
    const float* __restrict__ h_n, const float* __restrict__ c_n,
    const float* __restrict__ noise, const float* __restrict__ gsrc,
    const float* __restrict__ W_init, const float* __restrict__ b_init,
    const float* __restrict__ W_ih, const float* __restrict__ W_hh,
    const float* __restrict__ b_ih, const float* __restrict__ b_hh,
    const float* __restrict__ W_head, const float* __restrict__ b_head,
    float* __restrict__ out, int B, int T)
{
  __shared__ f32x2 sTIG[8 * 32];   // [k][j] = {v(j,k),    v(64+j,k)}  (i,g rows)
  __shared__ f32x2 sTFO[8 * 32];   // [k][j] = {v(32+j,k), v(96+j,k)}  (f,o rows)
  __shared__ __align__(16) float sm_h[2 * 36];   // per-half h, stride 36
  __shared__ __align__(16) float smL[2][56];     // 8 steps x 7 logits
  __shared__ __align__(16) float smS[2][56];     // 8 steps x 7 samples

  const int l    = threadIdx.x;     // one wave per block
  const int half = l >> 5;          // batch half 0/1
  const int j    = l & 31;          // state slot
  const int b    = blockIdx.x * 2 + half;

  // fused W_ih/bias tables (wave-local, in-order: no barrier needed)
  // v(r,k) = b_ih[r] + b_hh[r] + (k<7 ? W_ih[r*7+k] : 0)  — same value/order
  for (int i = l; i < 8 * 32; i += 64) {
    int k = i >> 5, jj = i & 31;
    float vi = b_ih[jj]      + b_hh[jj]      + ((k < 7) ? W_ih[jj * 7 + k]        : 0.f);
    float vf = b_ih[32 + jj] + b_hh[32 + jj] + ((k < 7) ? W_ih[(32 + jj) * 7 + k] : 0.f);
    float vg = b_ih[64 + jj] + b_hh[64 + jj] + ((k < 7) ? W_ih[(64 + jj) * 7 + k] : 0.f);
    float vo = b_ih[96 + jj] + b_hh[96 + jj] + ((k < 7) ? W_ih[(96 + jj) * 7 + k] : 0.f);
    sTIG[i] = (f32x2){vi, vg};
    sTFO[i] = (f32x2){vf, vo};
  }

  // ---- h0 init (x dies before weight registers are allocated) ----
  {
    float x[Hh + NDd];
#pragma unroll
    for (int i = 0; i < 8; i++)
      ((float4*)x)[i] = *(const float4*)&h_n[(size_t)b * Hh + 4 * i];
    ((float4*)x)[8] = *(const float4*)&noise[(size_t)b * NDd];
    ((float4*)x)[9] = *(const float4*)&noise[(size_t)b * NDd + 4];
    float a = b_init[j];
    const float* wr = &W_init[j * (Hh + NDd)];
#pragma unroll
    for (int k = 0; k < Hh + NDd; k++) a = fmaf(wr[k], x[k], a);
    sm_h[half * 36 + j] = a;
  }
  float c = c_n[(size_t)b * Hh + j];

  // ---- recurrent weights: rows rA = l (i|f row j), rB = l+64 (g|o row j),
  //      packed {rA, rB} -> 64 VGPRs/lane, shared by both batches ----
  f32x2 wPK[32];
  {
    const float* WA = W_hh + (size_t)l * Hh;
    const float* WB = W_hh + (size_t)(l + 64) * Hh;
#pragma unroll
    for (int kc = 0; kc < 8; kc++) {
      float4 wa = *(const float4*)&WA[4 * kc];
      float4 wb = *(const float4*)&WB[4 * kc];
      wPK[4 * kc + 0] = (f32x2){wa.x, wb.x};
      wPK[4 * kc + 1] = (f32x2){wa.y, wb.y};
      wPK[4 * kc + 2] = (f32x2){wa.z, wb.z};
      wPK[4 * kc + 3] = (f32x2){wa.w, wb.w};
    }
  }
  const f32x2* tbl = half ? sTFO : sTIG;   // own rows' init table

  // head weights: within each half, lane 4p+q (p<7) holds W_head[p][q+4m];
  // lanes with hp==7 carry zeros so the head can run unguarded.
  const int hp = (l & 31) >> 2;
  const int hq = l & 3;
  float whead[8];
  float bh = 0.f;
  if (hp < 7) {
#pragma unroll
    for (int m = 0; m < 8; m++) whead[m] = W_head[hp * Hh + hq + 4 * m];
    bh = b_head[hp];
  } else {
#pragma unroll
    for (int m = 0; m < 8; m++) whead[m] = 0.f;
  }

  const int r7 = l & 7;               // candidate index in 8-lane argmax group
  const int cpc = (r7 < 7) ? r7 : 6;
  const float* gL = gsrc + (size_t)b * Pp + cpc;
  const size_t strideT = (size_t)B * Pp;
  const size_t SOFF = (size_t)B * T * Pp;   // samples block offset (floats)

  int kA = 7, kB = 7;   // y0 = 0 -> bias-only column
  float* outL = out + (size_t)b * T * Pp;

  // pipelined gumbel input: u_cur feeds step t; u_{t+1} loads during step t
  float u_cur = gL[0];

  for (int t = 0; t < T; ++t) {
    // issue next step's gumbel load early (uniform select avoids OOB at t=T-1)
    int tn = (t + 1 < T) ? (t + 1) : t;
    float u_next = gL[(size_t)tn * strideT];

    // gumbel noise for THIS step (exact same expression text as rounds 1-9;
    // independent of the recurrence -> scheduler fills latency bubbles)
    float nv = -logf(-logf(u_cur + 1e-20f) + 1e-20f);

    // packed gate chains for BOTH batches (k-ascending, bit-identical rows)
    f32x2 accA = tbl[(kA << 5) + j];
    f32x2 accB = tbl[(kB << 5) + j];
#pragma unroll
    for (int kc = 0; kc < 8; kc++) {
      float4 hvA = *(const float4*)&sm_h[4 * kc];        // batch A h (uniform)
      float4 hvB = *(const float4*)&sm_h[36 + 4 * kc];   // batch B h (uniform)
      accA = fma2(wPK[4 * kc + 0], hvA.x, accA);
      accB = fma2(wPK[4 * kc + 0], hvB.x, accB);
      accA = fma2(wPK[4 * kc + 1], hvA.y, accA);
      accB = fma2(wPK[4 * kc + 1], hvB.y, accB);
      accA = fma2(wPK[4 * kc + 2], hvA.z, accA);
      accB = fma2(wPK[4 * kc + 2], hvB.z, accB);
      accA = fma2(wPK[4 * kc + 3], hvA.w, accA);
      accB = fma2(wPK[4 * kc + 3], hvB.w, accB);
    }

    // exchange: lanes<32 assemble batch A's (i,f,g,o); lanes>=32 batch B's
    float xAx = __shfl_xor(accA.x, 32), xAy = __shfl_xor(accA.y, 32);
    float xBx = __shfl_xor(accB.x, 32), xBy = __shfl_xor(accB.y, 32);
    float i_pre = (l < 32) ? accA.x : xBx;
    float g_pre = (l < 32) ? accA.y : xBy;
    float f_pre = (l < 32) ? xAx : accB.x;
    float o_pre = (l < 32) ? xAy : accB.y;

    // cell (exact expression text of rounds 1-9); lane<32 -> A, lane>=32 -> B
    float ig = 1.f / (1.f + expf(-i_pre));
    float fg = 1.f / (1.f + expf(-f_pre));
    float gg = tanhf(g_pre);
    float og = 1.f / (1.f + expf(-o_pre));
    float cc = fg * c + ig * gg;
    c = cc;
    float hj = og * tanhf(cc);
    sm_h[half * 36 + j] = hj;   // half 0 writes A, half 1 writes B

    // head: unguarded (hp==7 lanes compute zeros); same partial/reduce shape
    float lgp = 0.f;
#pragma unroll
    for (int m = 0; m < 8; m++)
      lgp = fmaf(whead[m], sm_h[half * 36 + hq + 4 * m], lgp);
    lgp += __shfl_xor(lgp, 1);
    lgp += __shfl_xor(lgp, 2);
    lgp += bh;

    // fan logit r7 of own half to this lane (lane 4*r7 of own half holds it)
    float Lr = __shfl(lgp, (l & 32) + 4 * cpc);

    // 8-lane lowest-index argmax butterfly (half-local groups)
    float bestv = (r7 < 7) ? (Lr + nv) : -__builtin_inff();
    int besti = r7;
#pragma unroll
    for (int mask = 1; mask <= 4; mask <<= 1) {
      float ov = __shfl_xor(bestv, mask);
      int   oi = __shfl_xor(besti, mask);
      if (ov > bestv || (ov == bestv && oi < besti)) { bestv = ov; besti = oi; }
    }
    kA = __shfl(besti, 0);
    kB = __shfl(besti, 32);
    int kme = (l < 32) ? kA : kB;

    // stage outputs (quad leaders p<7 of each half)
    if (hp < 7 && hq == 0) {
      int t8 = (t & 7) * Pp + hp;
      smL[half][t8] = lgp;
      smS[half][t8] = (kme == hp) ? 1.f : 0.f;
    }

    // flush every 8 steps: 14 float4 per batch half
    if ((t & 7) == 7) {
      int r = l & 31;
      if (r < 14) {
        size_t o = (size_t)(t - 7) * Pp + 4 * r;
        *(float4*)&outL[o]        = *(const float4*)&smL[half][4 * r];
        *(float4*)&outL[o + SOFF] = *(const float4*)&smS[half][4 * r];
      }
    } else if (t == T - 1) {
      int t0 = t & ~7;
      int cnt = (t - t0 + 1) * Pp;
      for (int i = l & 31; i < cnt; i += 32) {
        size_t o = (size_t)t0 * Pp + i;
        outL[o]        = smL[half][i];
        outL[o + SOFF] = smS[half][i];
      }
    }

    u_cur = u_next;
  }
}

extern "C" void kernel_launch(void* const* d_in, const int* in_sizes, int n_in,
                              void* d_out, int out_size, void* d_ws, size_t ws_size,
                              hipStream_t stream) {
  const float* h_n     = (const float*)d_in[0];
  const float* c_n     = (const float*)d_in[1];
  const float* noise   = (const float*)d_in[2];
  const float* gumbel  = (const float*)d_in[3];
  const float* W_init  = (const float*)d_in[4];
  const float* b_init  = (const float*)d_in[5];
  const float* W_ih    = (const float*)d_in[6];
  const float* W_hh    = (const float*)d_in[7];
  const float* b_ih    = (const float*)d_in[8];
  const float* b_hh    = (const float*)d_in[9];
  const float* W_head  = (const float*)d_in[10];
  const float* b_head  = (const float*)d_in[11];

  int B = in_sizes[0] / Hh;                 // 32768
  int n = in_sizes[3];                      // T*B*P
  int T = n / (B * Pp);                     // 128

  gen_decoder_kernel<<<dim3(B / 2), dim3(64), 0, stream>>>(
      h_n, c_n, noise, gumbel, W_init, b_init, W_ih, W_hh,
      b_ih, b_hh, W_head, b_head, (float*)d_out, B, T);
}